// Round 14
// baseline (770.739 us; speedup 1.0000x reference)
//
#include <hip/hip_runtime.h>
#include <hip/hip_bf16.h>
#include <stdint.h>

#define VOCAB 50257
#define VPAD2 50688   /* 99*512 */
#define DIM   640
#define SEQ   256
#define NBATCH 16
#define MROWS 4096    /* NBATCH*SEQ */

using bf16 = __hip_bfloat16;
typedef __attribute__((ext_vector_type(8))) short short8;
typedef __attribute__((ext_vector_type(4))) float f32x4;
struct bf16x4 { bf16 a, b, c, d; };

__device__ __forceinline__ void gld_lds16(const void* g, void* l) {
  __builtin_amdgcn_global_load_lds(
      (const __attribute__((address_space(1))) void*)g,
      (__attribute__((address_space(3))) void*)l, 16, 0, 0);
}

#define BAR() asm volatile("s_barrier" ::: "memory")
#define VMC0() asm volatile("s_waitcnt vmcnt(0)" ::: "memory")

// ---------------- embed: x = w_embed[idx] + w_pos  -> bf16 ----------------
__global__ void embed_kernel(const int* __restrict__ idx,
                             const float* __restrict__ we,
                             const float* __restrict__ wp,
                             bf16* __restrict__ xb) {
  int row = blockIdx.x;
  int t = row & (SEQ - 1);
  int tok = idx[row];
  const float* src = we + (long)tok * DIM;
  const float* pos = wp + (long)t * DIM;
  for (int d = threadIdx.x * 4; d < DIM; d += blockDim.x * 4) {
    float4 s = *(const float4*)(src + d);
    float4 p = *(const float4*)(pos + d);
    bf16x4 o = { __float2bfloat16(s.x + p.x), __float2bfloat16(s.y + p.y),
                 __float2bfloat16(s.z + p.z), __float2bfloat16(s.w + p.w) };
    *(bf16x4*)(xb + (long)row * DIM + d) = o;
  }
}

// ---------------- f32 -> bf16 convert (x4) with zero tail pad ----------------
__global__ void conv4_kernel(const float* __restrict__ src, bf16* __restrict__ dst,
                             long n_src, long n_dst) {
  long i = ((long)blockIdx.x * blockDim.x + threadIdx.x) * 4;
  long stride = (long)gridDim.x * blockDim.x * 4;
  for (; i < n_dst; i += stride) {
    float4 v = (i < n_src) ? *(const float4*)(src + i) : make_float4(0.f, 0.f, 0.f, 0.f);
    bf16x4 o = { __float2bfloat16(v.x), __float2bfloat16(v.y),
                 __float2bfloat16(v.z), __float2bfloat16(v.w) };
    *(bf16x4*)(dst + i) = o;
  }
}

// ---------------- v (16*256,640) -> vT (16,640,256) ----------------
__global__ void transpose_v(const bf16* __restrict__ v, bf16* __restrict__ vt) {
  long i = (long)blockIdx.x * blockDim.x + threadIdx.x;
  if (i >= (long)NBATCH * DIM * SEQ) return;
  int t = (int)(i & (SEQ - 1));
  long be = i >> 8;
  int e = (int)(be % DIM);
  int b = (int)(be / DIM);
  vt[i] = v[((long)b * SEQ + t) * DIM + e];
}

// ---------------- causal softmax: scores f32 -> P bf16 ----------------
__global__ void softmax_kernel(const float* __restrict__ sc, bf16* __restrict__ p) {
  int wid = threadIdx.x >> 6, lane = threadIdx.x & 63;
  int row = blockIdx.x * 4 + wid;
  int t = row & (SEQ - 1);
  const float* srow = sc + (long)row * SEQ;
  const float rsc = 0.03952847075210474f;  // 1/sqrt(640)
  float v[4];
  float mx = -1e30f;
#pragma unroll
  for (int i = 0; i < 4; ++i) {
    int s = lane + 64 * i;
    v[i] = (s <= t) ? srow[s] * rsc : -1e30f;
    mx = fmaxf(mx, v[i]);
  }
#pragma unroll
  for (int off = 32; off; off >>= 1) mx = fmaxf(mx, __shfl_xor(mx, off, 64));
  float sum = 0.f;
#pragma unroll
  for (int i = 0; i < 4; ++i) {
    int s = lane + 64 * i;
    v[i] = (s <= t) ? __expf(v[i] - mx) : 0.f;
    sum += v[i];
  }
#pragma unroll
  for (int off = 32; off; off >>= 1) sum += __shfl_xor(sum, off, 64);
  float inv = 1.f / sum;
#pragma unroll
  for (int i = 0; i < 4; ++i)
    p[(long)row * SEQ + lane + 64 * i] = __float2bfloat16(v[i] * inv);
}

// ========= 128x128 GEMM, 2-slot depth-1 pipeline (r5 config, small GEMMs) =========
template <int NT, typename OUT_T, bool BIAS>
__global__ __launch_bounds__(256, 4) void gemm_pipe(
    const bf16* __restrict__ Ag, const bf16* __restrict__ Bg,
    OUT_T* __restrict__ Cg, const float* __restrict__ bias,
    int K, int ldc, int Nstore, long sA, long sB, long sC) {
  __shared__ __align__(16) char lds[32768];   // 2 slots x [A 8KB | B 8KB]
  const int tid = threadIdx.x;
  const int lane = tid & 63, wv = tid >> 6;
  const int lr = lane & 15, h16 = lane >> 4;

  const int tm = blockIdx.x, tn = blockIdx.y, bz = blockIdx.z;
  const bf16* A = Ag + (long)bz * sA + (long)tm * 128 * K;
  const bf16* B = Bg + (long)bz * sB + (long)tn * 128 * K;

  int srcE[2], dstW[2];
#pragma unroll
  for (int j = 0; j < 2; ++j) {
    int d = j * 256 + tid;
    int b = d ^ ((d >> 3) & 3);
    srcE[j] = (b >> 2) * K + (b & 3) * 8;
    dstW[j] = (j * 256 + wv * 64) * 16;
  }
  const bf16* aS0 = A + srcE[0];
  const bf16* aS1 = A + srcE[1];
  const bf16* bS0 = B + srcE[0];
  const bf16* bS1 = B + srcE[1];
  auto STAGE = [&](int slot, int t) {
    int kOff = t * 32;
    gld_lds16(aS0 + kOff, lds + slot + dstW[0]);
    gld_lds16(aS1 + kOff, lds + slot + dstW[1]);
    gld_lds16(bS0 + kOff, lds + slot + 8192 + dstW[0]);
    gld_lds16(bS1 + kOff, lds + slot + 8192 + dstW[1]);
  };

  const int wr = (wv >> 1) * 64, wc = (wv & 1) * 64;
  int aoff[4], boff[4];
#pragma unroll
  for (int m = 0; m < 4; ++m) {
    int La = (wr + m * 16 + lr) * 64 + h16 * 16;
    aoff[m] = La ^ (((La >> 7) & 3) << 4);
    int Lb = (wc + m * 16 + lr) * 64 + h16 * 16;
    boff[m] = 8192 + (Lb ^ (((Lb >> 7) & 3) << 4));
  }

  f32x4 acc[4][4] = {};
  short8 a[4], b[4];

  STAGE(0, 0);
  VMC0();
  BAR();

#pragma unroll 2
  for (int t = 0; t < NT; ++t) {
    const int cur = (t & 1) * 16384;
    if (t + 1 < NT) STAGE(16384 - cur, t + 1);
#pragma unroll
    for (int m = 0; m < 4; ++m) a[m] = *(const short8*)(lds + cur + aoff[m]);
#pragma unroll
    for (int n = 0; n < 4; ++n) b[n] = *(const short8*)(lds + cur + boff[n]);
    __builtin_amdgcn_s_setprio(1);
#pragma unroll
    for (int m = 0; m < 4; ++m)
#pragma unroll
      for (int n = 0; n < 4; ++n)
        acc[m][n] = __builtin_amdgcn_mfma_f32_16x16x32_bf16(a[m], b[n], acc[m][n], 0, 0, 0);
    __builtin_amdgcn_s_setprio(0);
    if (t + 1 < NT) VMC0();
    BAR();
  }

  if constexpr (sizeof(OUT_T) == 4) {
    float* Cf = (float*)Cg + (long)bz * sC;
    float bv[4];
#pragma unroll
    for (int n = 0; n < 4; ++n) {
      int col = tn * 128 + wc + lr + n * 16;
      bv[n] = (BIAS && col < Nstore) ? bias[col] : 0.f;
    }
    char* reg = lds + wv * 8192;
    const int rowL = lane & 31, cb = lane >> 5;
#pragma unroll
    for (int mm = 0; mm < 2; ++mm) {
#pragma unroll
      for (int mp = 0; mp < 2; ++mp)
#pragma unroll
        for (int n = 0; n < 4; ++n) {
          f32x4 v = acc[mm * 2 + mp][n];
          v[0] += bv[n]; v[1] += bv[n]; v[2] += bv[n]; v[3] += bv[n];
          int col = lr + n * 16;
          int rho = mp * 16 + h16 * 4;
          int w = col * 32 + (rho ^ ((col & 7) << 2));
          *(f32x4*)(reg + w * 4) = v;
        }
      const long rowg = tm * 128 + wr + mm * 32 + rowL;
#pragma unroll
      for (int k = 0; k < 8; ++k) {
        f32x4 o;
#pragma unroll
        for (int c = 0; c < 4; ++c) {
          int col = k * 8 + cb * 4 + c;
          int w = col * 32 + (rowL ^ ((col & 7) << 2));
          o[c] = *(const float*)(reg + w * 4);
        }
        int gcol = tn * 128 + wc + k * 8 + cb * 4;
        float* dst = Cf + rowg * (long)ldc + gcol;
        if (gcol + 3 < Nstore) {
          *(f32x4*)dst = o;
        } else {
#pragma unroll
          for (int c = 0; c < 4; ++c)
            if (gcol + c < Nstore) dst[c] = o[c];
        }
      }
    }
  } else {
    OUT_T* C = Cg + (long)bz * sC;
    const int crow0 = tm * 128 + wr + h16 * 4;
    const int ccol0 = tn * 128 + wc + lr;
#pragma unroll
    for (int m = 0; m < 4; ++m)
#pragma unroll
      for (int n = 0; n < 4; ++n) {
        int col = ccol0 + n * 16;
        if (col < Nstore) {
#pragma unroll
          for (int j = 0; j < 4; ++j) {
            long row = crow0 + m * 16 + j;
            C[row * ldc + col] = __float2bfloat16(acc[m][n][j]);
          }
        }
      }
  }
}

// ========= logits GEMM: 64x512 block tile -- WRITE-SPAN experiment =========
// All r1-r13 variants write C in 512B chunks per block-row and pin at
// 2.1-2.6 TB/s total HBM (fillBuffer: 6.5 TB/s seq; r7's 16B nt-chunks:
// 1.6 TB/s -- monotone chunk-size -> rate). BN=512 makes each block write
// 2KB CONTIGUOUS per C-row (~one HBM page). 8 waves x 64x64/wave (r5-verified
// acc[4][4] body), BK=32, depth-1 2-slot ring (2x36KB=72KB -> 2 blocks/CU),
// identical swizzle formulas (zero bank conflicts since r4). B staged bytes
// rise ~4.5GB -- proven irrelevant (r10: 2GB vs 4.1GB no change; r12: FETCH
// 272MB vs 1GB no change).
__global__ __launch_bounds__(512, 4) void gemm_w(
    const bf16* __restrict__ Ag, const bf16* __restrict__ Bg,
    float* __restrict__ Cg, const float* __restrict__ bias) {
  __shared__ __align__(16) char lds[73728];   // 2 slots x [A 4KB | B 32KB]
  const int tid = threadIdx.x;
  const int lane = tid & 63, wv = tid >> 6;   // wv 0..7
  const int lr = lane & 15, h16 = lane >> 4;

  const int tm = blockIdx.x, tn = blockIdx.y;
  const bf16* A = Ag + (long)tm * 64 * DIM;
  const bf16* B = Bg + (long)tn * 512 * DIM;

  // A staging: 256 granules (4KB), threads 0-255 (waves 0-3), 1 each
  int srcA, dstA;
  {
    int d = tid & 255;
    int b = d ^ ((d >> 3) & 3);
    srcA = (b >> 2) * DIM + (b & 3) * 8;
    dstA = ((wv & 3) * 64) * 16;      // wave-uniform byte base (+lane*16 by HW)
  }
  // B staging: 2048 granules (32KB), 4 per thread
  int srcB[4], dstB[4];
#pragma unroll
  for (int j = 0; j < 4; ++j) {
    int d = j * 512 + tid;
    int b = d ^ ((d >> 3) & 3);
    srcB[j] = (b >> 2) * DIM + (b & 3) * 8;
    dstB[j] = (j * 512 + wv * 64) * 16;
  }
  auto STAGE = [&](int slot, int t) {
    int kOff = t * 32;
    if (tid < 256) gld_lds16(A + srcA + kOff, lds + slot + dstA);
#pragma unroll
    for (int j = 0; j < 4; ++j)
      gld_lds16(B + srcB[j] + kOff, lds + slot + 4096 + dstB[j]);
  };

  // ds_read offsets (swizzled; identical formula to r5/r9, zero conflicts)
  int aoff[4], boff[4];
#pragma unroll
  for (int m = 0; m < 4; ++m) {
    int La = (m * 16 + lr) * 64 + h16 * 16;           // A rows 0..63 (all waves)
    aoff[m] = La ^ (((La >> 7) & 3) << 4);
    int Lb = (wv * 64 + m * 16 + lr) * 64 + h16 * 16; // B rows wv*64..+63
    boff[m] = 4096 + (Lb ^ (((Lb >> 7) & 3) << 4));
  }

  f32x4 acc[4][4] = {};
  short8 a[4], b[4];

  STAGE(0, 0);
  VMC0();
  BAR();

#pragma unroll 2
  for (int t = 0; t < 20; ++t) {
    const int cur = (t & 1) * 36864;
    if (t + 1 < 20) STAGE(36864 - cur, t + 1);   // other slot; reads sealed @t-1
#pragma unroll
    for (int m = 0; m < 4; ++m) a[m] = *(const short8*)(lds + cur + aoff[m]);
#pragma unroll
    for (int n = 0; n < 4; ++n) b[n] = *(const short8*)(lds + cur + boff[n]);
    __builtin_amdgcn_s_setprio(1);
#pragma unroll
    for (int m = 0; m < 4; ++m)
#pragma unroll
      for (int n = 0; n < 4; ++n)
        acc[m][n] = __builtin_amdgcn_mfma_f32_16x16x32_bf16(a[m], b[n], acc[m][n], 0, 0, 0);
    __builtin_amdgcn_s_setprio(0);
    if (t + 1 < 20) VMC0();
    BAR();
  }

  // epilogue: C layout row=(lane>>4)*4+j, col=lane&15 (verified m89/m91)
  const int crow0 = tm * 64 + h16 * 4;
  const int ccol0 = tn * 512 + wv * 64 + lr;
  float bv[4];
#pragma unroll
  for (int n = 0; n < 4; ++n) {
    int col = ccol0 + n * 16;
    bv[n] = (col < VOCAB) ? bias[col] : 0.f;
  }
#pragma unroll
  for (int m = 0; m < 4; ++m)
#pragma unroll
    for (int n = 0; n < 4; ++n) {
      int col = ccol0 + n * 16;
      if (col < VOCAB) {
#pragma unroll
        for (int j = 0; j < 4; ++j)
          Cg[(long)(crow0 + m * 16 + j) * VOCAB + col] = acc[m][n][j] + bv[n];
      }
    }
}

extern "C" void kernel_launch(void* const* d_in, const int* in_sizes, int n_in,
                              void* d_out, int out_size, void* d_ws, size_t ws_size,
                              hipStream_t stream) {
  const int*   idx     = (const int*)d_in[0];
  const float* w_embed = (const float*)d_in[1];
  const float* w_pos   = (const float*)d_in[2];
  const float* wq      = (const float*)d_in[3];
  const float* wk      = (const float*)d_in[4];
  const float* wv      = (const float*)d_in[5];
  const float* w_out   = (const float*)d_in[6];
  const float* b_out   = (const float*)d_in[7];
  float* out = (float*)d_out;

  size_t off = 0;
  auto alloc = [&](size_t bytes) {
    void* p = (char*)d_ws + off;
    off += (bytes + 255) & ~(size_t)255;
    return p;
  };
  bf16* x_bf    = (bf16*)alloc((size_t)MROWS * DIM * 2);
  bf16* wqkv_bf = (bf16*)alloc((size_t)3 * DIM * DIM * 2);
  bf16* wout_bf = (bf16*)alloc((size_t)VPAD2 * DIM * 2);
  bf16* qkv     = (bf16*)alloc((size_t)3 * MROWS * DIM * 2);
  bf16* vT      = (bf16*)alloc((size_t)NBATCH * DIM * SEQ * 2);
  float* scores = (float*)alloc((size_t)NBATCH * SEQ * SEQ * 4);
  bf16* P       = (bf16*)alloc((size_t)NBATCH * SEQ * SEQ * 2);
  bf16* attn    = (bf16*)alloc((size_t)MROWS * DIM * 2);

  const long QKV_S = (long)MROWS * DIM;
  const long W_S   = (long)DIM * DIM;

  // 1. embed
  embed_kernel<<<MROWS, 256, 0, stream>>>(idx, w_embed, w_pos, x_bf);

  // 2. weight converts (bf16; w_out zero-padded to VPAD2 rows)
  conv4_kernel<<<256, 256, 0, stream>>>(wq, wqkv_bf,           W_S, W_S);
  conv4_kernel<<<256, 256, 0, stream>>>(wk, wqkv_bf + W_S,     W_S, W_S);
  conv4_kernel<<<256, 256, 0, stream>>>(wv, wqkv_bf + 2 * W_S, W_S, W_S);
  conv4_kernel<<<2048, 256, 0, stream>>>(w_out, wout_bf, (long)VOCAB * DIM, (long)VPAD2 * DIM);

  // 3. q,k,v = x @ {wq,wk,wv}^T   (K=640 -> NT=20)
  gemm_pipe<20, bf16, false><<<dim3(MROWS / 128, DIM / 128, 3), 256, 0, stream>>>(
      x_bf, wqkv_bf, qkv, nullptr, DIM, DIM, DIM, 0, W_S, QKV_S);

  // 4. vT per batch
  {
    long n = (long)NBATCH * DIM * SEQ;
    transpose_v<<<(int)((n + 255) / 256), 256, 0, stream>>>(qkv + 2 * QKV_S, vT);
  }

  // 5. scores[b] = q[b] @ k[b]^T  (K=640 -> NT=20)
  gemm_pipe<20, float, false><<<dim3(SEQ / 128, SEQ / 128, NBATCH), 256, 0, stream>>>(
      qkv, qkv + QKV_S, scores, nullptr, DIM, SEQ, SEQ,
      (long)SEQ * DIM, (long)SEQ * DIM, (long)SEQ * SEQ);

  // 6. causal softmax -> P bf16
  softmax_kernel<<<MROWS / 4, 256, 0, stream>>>(scores, P);

  // 7. attn[b] = P[b] @ vT[b]^T  (K=256 -> NT=8)
  gemm_pipe<8, bf16, false><<<dim3(SEQ / 128, DIM / 128, NBATCH), 256, 0, stream>>>(
      P, vT, attn, nullptr, SEQ, DIM, DIM,
      (long)SEQ * SEQ, (long)DIM * SEQ, (long)SEQ * DIM);

  // 8. logits = attn @ w_out^T + b_out  (64x512 tile: 2KB write spans)
  gemm_w<<<dim3(MROWS / 64, VPAD2 / 512), 512, 0, stream>>>(attn, wout_bf, out, b_out);
}

// Round 15
// 598.932 us; speedup vs baseline: 1.2869x; 1.2869x over previous
//
#include <hip/hip_runtime.h>
#include <hip/hip_bf16.h>
#include <stdint.h>

#define VOCAB 50257
#define VPAD  50432   /* 394*128 */
#define DIM   640
#define SEQ   256
#define NBATCH 16
#define MROWS 4096    /* NBATCH*SEQ */

using bf16 = __hip_bfloat16;
typedef __attribute__((ext_vector_type(8))) short short8;
typedef __attribute__((ext_vector_type(4))) float f32x4;
struct bf16x4 { bf16 a, b, c, d; };

__device__ __forceinline__ void gld_lds16(const void* g, void* l) {
  __builtin_amdgcn_global_load_lds(
      (const __attribute__((address_space(1))) void*)g,
      (__attribute__((address_space(3))) void*)l, 16, 0, 0);
}

#define BAR() asm volatile("s_barrier" ::: "memory")
#define VMC0() asm volatile("s_waitcnt vmcnt(0)" ::: "memory")

// ---------------- embed: x = w_embed[idx] + w_pos  -> bf16 ----------------
__global__ void embed_kernel(const int* __restrict__ idx,
                             const float* __restrict__ we,
                             const float* __restrict__ wp,
                             bf16* __restrict__ xb) {
  int row = blockIdx.x;
  int t = row & (SEQ - 1);
  int tok = idx[row];
  const float* src = we + (long)tok * DIM;
  const float* pos = wp + (long)t * DIM;
  for (int d = threadIdx.x * 4; d < DIM; d += blockDim.x * 4) {
    float4 s = *(const float4*)(src + d);
    float4 p = *(const float4*)(pos + d);
    bf16x4 o = { __float2bfloat16(s.x + p.x), __float2bfloat16(s.y + p.y),
                 __float2bfloat16(s.z + p.z), __float2bfloat16(s.w + p.w) };
    *(bf16x4*)(xb + (long)row * DIM + d) = o;
  }
}

// ---------------- f32 -> bf16 convert (x4) with zero tail pad ----------------
__global__ void conv4_kernel(const float* __restrict__ src, bf16* __restrict__ dst,
                             long n_src, long n_dst) {
  long i = ((long)blockIdx.x * blockDim.x + threadIdx.x) * 4;
  long stride = (long)gridDim.x * blockDim.x * 4;
  for (; i < n_dst; i += stride) {
    float4 v = (i < n_src) ? *(const float4*)(src + i) : make_float4(0.f, 0.f, 0.f, 0.f);
    bf16x4 o = { __float2bfloat16(v.x), __float2bfloat16(v.y),
                 __float2bfloat16(v.z), __float2bfloat16(v.w) };
    *(bf16x4*)(dst + i) = o;
  }
}

// ---------------- causal softmax: scores f32 -> P bf16 ----------------
__global__ void softmax_kernel(const float* __restrict__ sc, bf16* __restrict__ p) {
  int wid = threadIdx.x >> 6, lane = threadIdx.x & 63;
  int row = blockIdx.x * 4 + wid;
  int t = row & (SEQ - 1);
  const float* srow = sc + (long)row * SEQ;
  const float rsc = 0.03952847075210474f;  // 1/sqrt(640)
  float v[4];
  float mx = -1e30f;
#pragma unroll
  for (int i = 0; i < 4; ++i) {
    int s = lane + 64 * i;
    v[i] = (s <= t) ? srow[s] * rsc : -1e30f;
    mx = fmaxf(mx, v[i]);
  }
#pragma unroll
  for (int off = 32; off; off >>= 1) mx = fmaxf(mx, __shfl_xor(mx, off, 64));
  float sum = 0.f;
#pragma unroll
  for (int i = 0; i < 4; ++i) {
    int s = lane + 64 * i;
    v[i] = (s <= t) ? __expf(v[i] - mx) : 0.f;
    sum += v[i];
  }
#pragma unroll
  for (int off = 32; off; off >>= 1) sum += __shfl_xor(sum, off, 64);
  float inv = 1.f / sum;
#pragma unroll
  for (int i = 0; i < 4; ++i)
    p[(long)row * SEQ + lane + 64 * i] = __float2bfloat16(v[i] * inv);
}

// ========= 128x128 GEMM, 2-slot depth-1 pipeline (r5 config) =========
// TRV=true (bf16 path only): write C transposed per batch -> vT[b][e][t]
// (b = row>>8, t = row&255, e = col), fusing the V-transpose into the epilogue.
template <int NT, typename OUT_T, bool BIAS, bool TRV>
__global__ __launch_bounds__(256, 4) void gemm_pipe(
    const bf16* __restrict__ Ag, const bf16* __restrict__ Bg,
    OUT_T* __restrict__ Cg, const float* __restrict__ bias,
    int K, int ldc, int Nstore, long sA, long sB, long sC) {
  __shared__ __align__(16) char lds[32768];   // 2 slots x [A 8KB | B 8KB]
  const int tid = threadIdx.x;
  const int lane = tid & 63, wv = tid >> 6;
  const int lr = lane & 15, h16 = lane >> 4;

  const int tm = blockIdx.x, tn = blockIdx.y, bz = blockIdx.z;
  const bf16* A = Ag + (long)bz * sA + (long)tm * 128 * K;
  const bf16* B = Bg + (long)bz * sB + (long)tn * 128 * K;

  int srcE[2], dstW[2];
#pragma unroll
  for (int j = 0; j < 2; ++j) {
    int d = j * 256 + tid;
    int b = d ^ ((d >> 3) & 3);
    srcE[j] = (b >> 2) * K + (b & 3) * 8;
    dstW[j] = (j * 256 + wv * 64) * 16;
  }
  const bf16* aS0 = A + srcE[0];
  const bf16* aS1 = A + srcE[1];
  const bf16* bS0 = B + srcE[0];
  const bf16* bS1 = B + srcE[1];
  auto STAGE = [&](int slot, int t) {
    int kOff = t * 32;
    gld_lds16(aS0 + kOff, lds + slot + dstW[0]);
    gld_lds16(aS1 + kOff, lds + slot + dstW[1]);
    gld_lds16(bS0 + kOff, lds + slot + 8192 + dstW[0]);
    gld_lds16(bS1 + kOff, lds + slot + 8192 + dstW[1]);
  };

  const int wr = (wv >> 1) * 64, wc = (wv & 1) * 64;
  int aoff[4], boff[4];
#pragma unroll
  for (int m = 0; m < 4; ++m) {
    int La = (wr + m * 16 + lr) * 64 + h16 * 16;
    aoff[m] = La ^ (((La >> 7) & 3) << 4);
    int Lb = (wc + m * 16 + lr) * 64 + h16 * 16;
    boff[m] = 8192 + (Lb ^ (((Lb >> 7) & 3) << 4));
  }

  f32x4 acc[4][4] = {};
  short8 a[4], b[4];

  STAGE(0, 0);
  VMC0();
  BAR();

#pragma unroll 2
  for (int t = 0; t < NT; ++t) {
    const int cur = (t & 1) * 16384;
    if (t + 1 < NT) STAGE(16384 - cur, t + 1);
#pragma unroll
    for (int m = 0; m < 4; ++m) a[m] = *(const short8*)(lds + cur + aoff[m]);
#pragma unroll
    for (int n = 0; n < 4; ++n) b[n] = *(const short8*)(lds + cur + boff[n]);
    __builtin_amdgcn_s_setprio(1);
#pragma unroll
    for (int m = 0; m < 4; ++m)
#pragma unroll
      for (int n = 0; n < 4; ++n)
        acc[m][n] = __builtin_amdgcn_mfma_f32_16x16x32_bf16(a[m], b[n], acc[m][n], 0, 0, 0);
    __builtin_amdgcn_s_setprio(0);
    if (t + 1 < NT) VMC0();
    BAR();
  }

  if constexpr (sizeof(OUT_T) == 4) {
    // wide-store epilogue via per-wave LDS transpose (cached stores)
    float* Cf = (float*)Cg + (long)bz * sC;
    float bv[4];
#pragma unroll
    for (int n = 0; n < 4; ++n) {
      int col = tn * 128 + wc + lr + n * 16;
      bv[n] = (BIAS && col < Nstore) ? bias[col] : 0.f;
    }
    char* reg = lds + wv * 8192;
    const int rowL = lane & 31, cb = lane >> 5;
#pragma unroll
    for (int mm = 0; mm < 2; ++mm) {
#pragma unroll
      for (int mp = 0; mp < 2; ++mp)
#pragma unroll
        for (int n = 0; n < 4; ++n) {
          f32x4 v = acc[mm * 2 + mp][n];
          v[0] += bv[n]; v[1] += bv[n]; v[2] += bv[n]; v[3] += bv[n];
          int col = lr + n * 16;
          int rho = mp * 16 + h16 * 4;
          int w = col * 32 + (rho ^ ((col & 7) << 2));
          *(f32x4*)(reg + w * 4) = v;
        }
      const long rowg = tm * 128 + wr + mm * 32 + rowL;
#pragma unroll
      for (int k = 0; k < 8; ++k) {
        f32x4 o;
#pragma unroll
        for (int c = 0; c < 4; ++c) {
          int col = k * 8 + cb * 4 + c;
          int w = col * 32 + (rowL ^ ((col & 7) << 2));
          o[c] = *(const float*)(reg + w * 4);
        }
        int gcol = tn * 128 + wc + k * 8 + cb * 4;
        float* dst = Cf + rowg * (long)ldc + gcol;
        if (gcol + 3 < Nstore) {
          *(f32x4*)dst = o;
        } else {
#pragma unroll
          for (int c = 0; c < 4; ++c)
            if (gcol + c < Nstore) dst[c] = o[c];
        }
      }
    }
  } else {
    OUT_T* C = Cg + (long)bz * sC;
    const int crow0 = tm * 128 + wr + h16 * 4;
    const int ccol0 = tn * 128 + wc + lr;
#pragma unroll
    for (int m = 0; m < 4; ++m)
#pragma unroll
      for (int n = 0; n < 4; ++n) {
        int col = ccol0 + n * 16;
        if (col < Nstore) {
#pragma unroll
          for (int j = 0; j < 4; ++j) {
            long row = crow0 + m * 16 + j;
            if constexpr (TRV) {
              // vT[b][e][t]: fused V transpose
              C[((long)(row >> 8) * DIM + col) * SEQ + (row & 255)] =
                  __float2bfloat16(acc[m][n][j]);
            } else {
              C[row * ldc + col] = __float2bfloat16(acc[m][n][j]);
            }
          }
        }
      }
  }
}

// ========= scores: 64x64-tile GEMM, causal tile-skip =========
// scores[b] = q[b] @ k[b]^T. 256 blocks (4x4x16) -> full CU coverage
// (128-tile gave 64 blocks = 25% of CUs, latency-dominated). Tiles with
// tn>tm are fully above the causal diagonal -- never read by softmax -> skip.
// 4 waves (2x2), each 32x32 (acc[2][2]); same staging/swizzle formulas as
// gemm_pipe (identical 64B-row geometry, bank-verified 0-conflict since r4).
__global__ __launch_bounds__(256, 6) void scores64(
    const bf16* __restrict__ qg, const bf16* __restrict__ kg,
    float* __restrict__ sc) {
  const int tm = blockIdx.x, tn = blockIdx.y, bz = blockIdx.z;
  if (tn > tm) return;   // fully-masked causal tile
  __shared__ __align__(16) char lds[16384];   // 2 slots x [A 4KB | B 4KB]
  const int tid = threadIdx.x;
  const int lane = tid & 63, wv = tid >> 6;
  const int lr = lane & 15, h16 = lane >> 4;

  const bf16* A = qg + (long)bz * SEQ * DIM + (long)tm * 64 * DIM;
  const bf16* B = kg + (long)bz * SEQ * DIM + (long)tn * 64 * DIM;

  int srcE, dstW;
  {
    int d = tid;                     // 256 granules per 4KB half, 1 each
    int b = d ^ ((d >> 3) & 3);
    srcE = (b >> 2) * DIM + (b & 3) * 8;
    dstW = (wv * 64) * 16;
  }
  auto STAGE = [&](int slot, int t) {
    int kOff = t * 32;
    gld_lds16(A + srcE + kOff, lds + slot + dstW);
    gld_lds16(B + srcE + kOff, lds + slot + 4096 + dstW);
  };

  const int wm = wv >> 1, wn = wv & 1;
  int aoff[2], boff[2];
#pragma unroll
  for (int m = 0; m < 2; ++m) {
    int La = (wm * 32 + m * 16 + lr) * 64 + h16 * 16;
    aoff[m] = La ^ (((La >> 7) & 3) << 4);
    int Lb = (wn * 32 + m * 16 + lr) * 64 + h16 * 16;
    boff[m] = 4096 + (Lb ^ (((Lb >> 7) & 3) << 4));
  }

  f32x4 acc[2][2] = {};
  short8 a[2], b[2];

  STAGE(0, 0);
  VMC0();
  BAR();

#pragma unroll 2
  for (int t = 0; t < 20; ++t) {
    const int cur = (t & 1) * 8192;
    if (t + 1 < 20) STAGE(8192 - cur, t + 1);
#pragma unroll
    for (int m = 0; m < 2; ++m) a[m] = *(const short8*)(lds + cur + aoff[m]);
#pragma unroll
    for (int n = 0; n < 2; ++n) b[n] = *(const short8*)(lds + cur + boff[n]);
    __builtin_amdgcn_s_setprio(1);
#pragma unroll
    for (int m = 0; m < 2; ++m)
#pragma unroll
      for (int n = 0; n < 2; ++n)
        acc[m][n] = __builtin_amdgcn_mfma_f32_16x16x32_bf16(a[m], b[n], acc[m][n], 0, 0, 0);
    __builtin_amdgcn_s_setprio(0);
    if (t + 1 < 20) VMC0();
    BAR();
  }

  float* S = sc + (long)bz * SEQ * SEQ;
  const int crow0 = tm * 64 + wm * 32 + h16 * 4;
  const int ccol0 = tn * 64 + wn * 32 + lr;
#pragma unroll
  for (int m = 0; m < 2; ++m)
#pragma unroll
    for (int n = 0; n < 2; ++n)
#pragma unroll
      for (int j = 0; j < 4; ++j)
        S[(long)(crow0 + m * 16 + j) * SEQ + ccol0 + n * 16] = acc[m][n][j];
}

// ========= logits GEMM: r9's gemm8 VERBATIM (best measured: 485us) =========
// 128x128 tile, 8 waves (2Mx4N, 64x32 each, acc[4][2]=32 regs), BK=32,
// depth-1 2-slot ring, tm-fastest grid, 67% occupancy. r1-r14 established
// this sits at the 2-phase-family structural ceiling for K=640 (all axes
// falsified: depth/barriers/TLP/bytes/write-locality/span); the documented
// escape (8-phase 256^2, T2-T5) requires K-amortization that K=640 lacks (r2).
__global__ __launch_bounds__(512, 6) void gemm8(
    const bf16* __restrict__ Ag, const bf16* __restrict__ Bg,
    float* __restrict__ Cg, const float* __restrict__ bias) {
  __shared__ __align__(16) char lds[32768];   // 2 slots x [A 8KB | B 8KB]
  const int tid = threadIdx.x;
  const int lane = tid & 63, wv = tid >> 6;
  const int lr = lane & 15, h16 = lane >> 4;

  const int tm = blockIdx.x, tn = blockIdx.y;
  const bf16* A = Ag + (long)tm * 128 * DIM;
  const bf16* B = Bg + (long)tn * 128 * DIM;

  int srcE, dstW;
  {
    int d = tid;
    int b = d ^ ((d >> 3) & 3);
    srcE = (b >> 2) * DIM + (b & 3) * 8;
    dstW = (wv * 64) * 16;
  }
  const bf16* aS = A + srcE;
  const bf16* bS = B + srcE;
  auto STAGE = [&](int slot, int t) {
    int kOff = t * 32;
    gld_lds16(aS + kOff, lds + slot + dstW);
    gld_lds16(bS + kOff, lds + slot + 8192 + dstW);
  };

  const int wr = (wv >> 2) * 64, wc = (wv & 3) * 32;
  int aoff[4], boff[2];
#pragma unroll
  for (int m = 0; m < 4; ++m) {
    int La = (wr + m * 16 + lr) * 64 + h16 * 16;
    aoff[m] = La ^ (((La >> 7) & 3) << 4);
  }
#pragma unroll
  for (int n = 0; n < 2; ++n) {
    int Lb = (wc + n * 16 + lr) * 64 + h16 * 16;
    boff[n] = 8192 + (Lb ^ (((Lb >> 7) & 3) << 4));
  }

  f32x4 acc[4][2] = {};
  short8 a[4], b[2];

  STAGE(0, 0);
  VMC0();
  BAR();

#pragma unroll 2
  for (int t = 0; t < 20; ++t) {
    const int cur = (t & 1) * 16384;
    if (t + 1 < 20) STAGE(16384 - cur, t + 1);
#pragma unroll
    for (int m = 0; m < 4; ++m) a[m] = *(const short8*)(lds + cur + aoff[m]);
#pragma unroll
    for (int n = 0; n < 2; ++n) b[n] = *(const short8*)(lds + cur + boff[n]);
    __builtin_amdgcn_s_setprio(1);
#pragma unroll
    for (int m = 0; m < 4; ++m)
#pragma unroll
      for (int n = 0; n < 2; ++n)
        acc[m][n] = __builtin_amdgcn_mfma_f32_16x16x32_bf16(a[m], b[n], acc[m][n], 0, 0, 0);
    __builtin_amdgcn_s_setprio(0);
    if (t + 1 < 20) VMC0();
    BAR();
  }

  const int crow0 = tm * 128 + wr + h16 * 4;
  const int ccol0 = tn * 128 + wc + lr;
  float bv[2];
#pragma unroll
  for (int n = 0; n < 2; ++n) {
    int col = ccol0 + n * 16;
    bv[n] = (col < VOCAB) ? bias[col] : 0.f;
  }
#pragma unroll
  for (int m = 0; m < 4; ++m)
#pragma unroll
    for (int n = 0; n < 2; ++n) {
      int col = ccol0 + n * 16;
      if (col < VOCAB) {
#pragma unroll
        for (int j = 0; j < 4; ++j)
          Cg[(long)(crow0 + m * 16 + j) * VOCAB + col] = acc[m][n][j] + bv[n];
      }
    }
}

extern "C" void kernel_launch(void* const* d_in, const int* in_sizes, int n_in,
                              void* d_out, int out_size, void* d_ws, size_t ws_size,
                              hipStream_t stream) {
  const int*   idx     = (const int*)d_in[0];
  const float* w_embed = (const float*)d_in[1];
  const float* w_pos   = (const float*)d_in[2];
  const float* wq      = (const float*)d_in[3];
  const float* wk      = (const float*)d_in[4];
  const float* wv      = (const float*)d_in[5];
  const float* w_out   = (const float*)d_in[6];
  const float* b_out   = (const float*)d_in[7];
  float* out = (float*)d_out;

  size_t off = 0;
  auto alloc = [&](size_t bytes) {
    void* p = (char*)d_ws + off;
    off += (bytes + 255) & ~(size_t)255;
    return p;
  };
  bf16* x_bf    = (bf16*)alloc((size_t)MROWS * DIM * 2);
  bf16* wqkv_bf = (bf16*)alloc((size_t)3 * DIM * DIM * 2);
  bf16* wout_bf = (bf16*)alloc((size_t)VPAD * DIM * 2);
  bf16* qkv     = (bf16*)alloc((size_t)2 * MROWS * DIM * 2);  // q,k
  bf16* vT      = (bf16*)alloc((size_t)NBATCH * DIM * SEQ * 2);
  float* scores = (float*)alloc((size_t)NBATCH * SEQ * SEQ * 4);
  bf16* P       = (bf16*)alloc((size_t)NBATCH * SEQ * SEQ * 2);
  bf16* attn    = (bf16*)alloc((size_t)MROWS * DIM * 2);

  const long QKV_S = (long)MROWS * DIM;
  const long W_S   = (long)DIM * DIM;

  // 1. embed
  embed_kernel<<<MROWS, 256, 0, stream>>>(idx, w_embed, w_pos, x_bf);

  // 2. weight converts (bf16; w_out zero-padded to VPAD rows)
  conv4_kernel<<<256, 256, 0, stream>>>(wq, wqkv_bf,           W_S, W_S);
  conv4_kernel<<<256, 256, 0, stream>>>(wk, wqkv_bf + W_S,     W_S, W_S);
  conv4_kernel<<<256, 256, 0, stream>>>(wv, wqkv_bf + 2 * W_S, W_S, W_S);
  conv4_kernel<<<2048, 256, 0, stream>>>(w_out, wout_bf, (long)VOCAB * DIM, (long)VPAD * DIM);

  // 3a. q,k = x @ {wq,wk}^T   (K=640 -> NT=20)
  gemm_pipe<20, bf16, false, false><<<dim3(MROWS / 128, DIM / 128, 2), 256, 0, stream>>>(
      x_bf, wqkv_bf, qkv, nullptr, DIM, DIM, DIM, 0, W_S, QKV_S);

  // 3b. vT = (x @ wv^T)^T per batch  (transpose fused into epilogue)
  gemm_pipe<20, bf16, false, true><<<dim3(MROWS / 128, DIM / 128, 1), 256, 0, stream>>>(
      x_bf, wqkv_bf + 2 * W_S, vT, nullptr, DIM, DIM, DIM, 0, 0, 0);

  // 4. scores[b] = q[b] @ k[b]^T  (64x64 tiles, causal skip)
  scores64<<<dim3(4, 4, NBATCH), 256, 0, stream>>>(qkv, qkv + QKV_S, scores);

  // 5. causal softmax -> P bf16
  softmax_kernel<<<MROWS / 4, 256, 0, stream>>>(scores, P);

  // 6. attn[b] = P[b] @ vT[b]^T  (K=256 -> NT=8)
  gemm_pipe<8, bf16, false, false><<<dim3(SEQ / 128, DIM / 128, NBATCH), 256, 0, stream>>>(
      P, vT, attn, nullptr, SEQ, DIM, DIM,
      (long)SEQ * SEQ, (long)DIM * SEQ, (long)SEQ * DIM);

  // 7. logits = attn @ w_out^T + b_out  (r9 gemm8: best-measured config)
  gemm8<<<dim3(MROWS / 128, VPAD / 128), 512, 0, stream>>>(attn, wout_bf, out, b_out);
}